// Round 10
// baseline (206.233 us; speedup 1.0000x reference)
//
#include <hip/hip_runtime.h>
#include <hip/hip_bf16.h>
#include <stdint.h>

typedef __bf16 bf16x8 __attribute__((ext_vector_type(8)));
typedef float  f32x4  __attribute__((ext_vector_type(4)));
typedef float  f32x16 __attribute__((ext_vector_type(16)));
typedef __attribute__((address_space(1))) uint32_t u32_g;
typedef __attribute__((address_space(3))) uint32_t u32_l;
typedef unsigned short u16;
typedef u16 u16x4 __attribute__((ext_vector_type(4)));

__device__ __forceinline__ void gload16(const void* g, void* l) {
    __builtin_amdgcn_global_load_lds((u32_g*)g, (u32_l*)l, 16, 0, 0);
}

__device__ __forceinline__ u16 bf16bits(float v) {
    __bf16 h = (__bf16)v;
    return __builtin_bit_cast(u16, h);
}

// ---------------------------------------------------------------------------
// k_prep:
//   b <  512 : WT[z][kc'] = bf16(w_out[c*32+e][z]),  kc' = e*32 + c
//   b <  576 : WcatT[n][k] = bf16(n<32 ? w1[k][n] : w2[k][n-32])
//   else     : rnorm[i][j] = 1 / (mask^T mask + 1e-3), one block per i
// ---------------------------------------------------------------------------
__global__ __launch_bounds__(256) void k_prep(const float* __restrict__ w_out,
                                              const float* __restrict__ mask,
                                              const float* __restrict__ w1,
                                              const float* __restrict__ w2,
                                              u16* __restrict__ WT,
                                              u16* __restrict__ WcatT,
                                              float* __restrict__ rnormv) {
    __shared__ float mcol[256];
    const int b = blockIdx.x, t = threadIdx.x;
    if (b < 512) {
        int idx = b * 256 + t;            // z*1024 + kc'
        int z = idx >> 10, kc = idx & 1023;
        int c = kc & 31, e = kc >> 5;
        WT[idx] = bf16bits(w_out[(c * 32 + e) * 128 + z]);
    } else if (b < 576) {
        int idx = (b - 512) * 256 + t;
        int n = idx >> 8, k = idx & 255;
        float v = (n < 32) ? w1[k * 32 + n] : w2[k * 32 + (n - 32)];
        WcatT[idx] = bf16bits(v);
    } else {
        int i = b - 576;
        mcol[t] = mask[(size_t)t * 256 + i];
        __syncthreads();
        float acc = 1e-3f;
#pragma unroll 8
        for (int s = 0; s < 256; ++s)
            acc += mcol[s] * mask[(size_t)s * 256 + t];
        rnormv[i * 256 + t] = 1.0f / acc;
    }
}

// ---------------------------------------------------------------------------
// k_lnproj: LayerNorm + dual projection via MFMA (unchanged).
// ---------------------------------------------------------------------------
__global__ __launch_bounds__(256, 2) void k_lnproj(
        const float* __restrict__ M, const float* __restrict__ mask,
        const float* __restrict__ lnw, const float* __restrict__ lnb,
        const float* __restrict__ b1, const float* __restrict__ b2,
        const u16* __restrict__ WcatT,
        u16* __restrict__ AT, u16* __restrict__ BT) {
    __shared__ __align__(16) u16 sh[32768];   // 64 KB
    const int tid = threadIdx.x, lane = tid & 63, w = tid >> 6;
    const int i = blockIdx.x, s0 = blockIdx.y * 64;

#pragma unroll
    for (int p = 0; p < 8; ++p) {
        int flat = p * 256 + tid;
        int r = flat >> 5, slot = flat & 31;
        int gs = slot ^ (r & 7);
        const char* src = (const char*)WcatT + (size_t)r * 512 + (size_t)gs * 16;
        char* dst = (char*)sh + 32768 + (size_t)(p * 256 + (tid & ~63)) * 16;
        gload16(src, dst);
    }

    float4 wv = *(const float4*)(lnw + lane * 4);
    float4 bv = *(const float4*)(lnb + lane * 4);
    float4 xv[16];
#pragma unroll
    for (int it = 0; it < 16; ++it) {
        int s = s0 + w * 16 + it;
        xv[it] = *(const float4*)(M + ((size_t)s * 256 + i) * 256 + lane * 4);
    }
#pragma unroll
    for (int it = 0; it < 16; ++it) {
        int row = w * 16 + it;
        float4 x = xv[it];
        float s1 = x.x + x.y + x.z + x.w;
        float s2 = x.x * x.x + x.y * x.y + x.z * x.z + x.w * x.w;
#pragma unroll
        for (int o = 1; o < 64; o <<= 1) {
            s1 += __shfl_xor(s1, o);
            s2 += __shfl_xor(s2, o);
        }
        float mu   = s1 * 0.00390625f;
        float var  = s2 * 0.00390625f - mu * mu;
        float rstd = rsqrtf(var + 1e-5f);
        u16x4 pk;
        pk[0] = bf16bits((x.x - mu) * rstd * wv.x + bv.x);
        pk[1] = bf16bits((x.y - mu) * rstd * wv.y + bv.y);
        pk[2] = bf16bits((x.z - mu) * rstd * wv.z + bv.z);
        pk[3] = bf16bits((x.w - mu) * rstd * wv.w + bv.w);
        int byte = (row * 512 + lane * 8) ^ ((row & 7) << 4);
        *(u16x4*)((char*)sh + byte) = pk;
    }
    __syncthreads();

    f32x4 acc[4] = {};
#pragma unroll
    for (int kk = 0; kk < 8; ++kk) {
        int kb = kk * 64 + ((lane >> 4) << 4);
        int arow = w * 16 + (lane & 15);
        bf16x8 af = *(const bf16x8*)((const char*)sh +
                     ((arow * 512 + kb) ^ ((arow & 7) << 4)));
#pragma unroll
        for (int f = 0; f < 4; ++f) {
            int nrow = f * 16 + (lane & 15);
            bf16x8 bfr = *(const bf16x8*)((const char*)sh + 32768 +
                          ((nrow * 512 + kb) ^ ((nrow & 7) << 4)));
            acc[f] = __builtin_amdgcn_mfma_f32_16x16x32_bf16(af, bfr, acc[f], 0, 0, 0);
        }
    }

    const int sb = s0 + w * 16 + ((lane >> 4) << 2);
    float mk[4];
#pragma unroll
    for (int r = 0; r < 4; ++r) mk[r] = mask[(size_t)(sb + r) * 256 + i];
#pragma unroll
    for (int f = 0; f < 4; ++f) {
        int col = f * 16 + (lane & 15);
        float bias = (col < 32) ? b1[col] : b2[col - 32];
        u16* dst = ((col < 32) ? AT : BT) + ((size_t)i * 32 + (col & 31)) * 256 + sb;
        u16x4 pk;
#pragma unroll
        for (int r = 0; r < 4; ++r)
            pk[r] = bf16bits((acc[f][r] + bias) * mk[r]);
        *(u16x4*)dst = pk;
    }
}

// ---------------------------------------------------------------------------
// k_fused v10: GEMM1 with NO LDS staging — per-wave direct L2->VGPR operand
// streams (square-XCD mapping keeps panels XCD-L2-resident; per-tile working
// set fits L1). Zero barriers/waitcnt in the K-loop; fully unrolled so the
// compiler hoists the 64 independent dwordx4 loads. LDS = P[32][1024] only
// (64 KB -> 2 blocks/CU). One __syncthreads before GEMM2. GEMM2 = R9.
// ---------------------------------------------------------------------------
__global__ __launch_bounds__(512, 4) void k_fused(
        const u16* __restrict__ AT, const u16* __restrict__ BT,
        const u16* __restrict__ WT, const float* __restrict__ rnormv,
        const float* __restrict__ b_out, float* __restrict__ out) {
    __shared__ __align__(16) u16 sh[32768];   // 64 KB: P[32][1024]
    const int tid  = threadIdx.x;
    const int lane = tid & 63;
    const int wid  = tid >> 6;
    const int wr   = wid >> 2, wc = wid & 3;   // GEMM1: 2 x 4 wave grid
    const int l15  = lane & 15;
    const int q16  = lane >> 4;
    // Square-region XCD mapping: XCD x = lid&7 owns bx in [(x&3)*16,+16),
    // by in [(x>>2)*16,+16). Per-XCD L2 set: AT 1MB + BT 2MB + WT 0.25MB.
    const int lid = blockIdx.x;
    const int x   = lid & 7;
    const int kk_ = lid >> 3;                  // 0..255
    const int bx  = (x & 3) * 16 + (kk_ & 15);
    const int by  = (x >> 2) * 16 + (kk_ >> 4);
    const int m0 = bx * 128, n0 = by * 256;

    f32x4 acc[4][4] = {};

    // per-wave operand base pointers (row of mi/nj = base + {mi,nj}*16 rows)
    const u16* Abase = AT + (size_t)(m0 + wr * 64 + l15) * 256 + q16 * 8;
    const u16* Bbase = BT + (size_t)(n0 + wc * 64 + l15) * 256 + q16 * 8;

#pragma unroll
    for (int t = 0; t < 8; ++t) {
        bf16x8 af[4], bfr[4];
#pragma unroll
        for (int mi = 0; mi < 4; ++mi)
            af[mi] = *(const bf16x8*)(Abase + (size_t)mi * 4096 + t * 32);
#pragma unroll
        for (int nj = 0; nj < 4; ++nj)
            bfr[nj] = *(const bf16x8*)(Bbase + (size_t)nj * 4096 + t * 32);
        __builtin_amdgcn_s_setprio(1);
#pragma unroll
        for (int mi = 0; mi < 4; ++mi)
#pragma unroll
            for (int nj = 0; nj < 4; ++nj)
                acc[mi][nj] = __builtin_amdgcn_mfma_f32_16x16x32_bf16(
                    af[mi], bfr[nj], acc[mi][nj], 0, 0, 0);
        __builtin_amdgcn_s_setprio(0);
    }

    // ---- hoisted GEMM2 / epilogue loads (no dependency on P) ----
    const int z0  = (wid & 3) * 32;
    const int hi  = lane >> 5;         // 0/1
    const int p32 = lane & 31;
    const u16* wtrow = WT + (size_t)(z0 + p32) * 1024 + hi * 8;
    const int i0 = bx * 4, j0 = by * 8;
    bf16x8 wbr[8];
    float  rn[16];
    float  bz = 0.f;
    if (wid < 4) {
#pragma unroll
        for (int d = 0; d < 8; ++d)
            wbr[d] = *(const bf16x8*)(wtrow + d * 16);
        bz = b_out[z0 + p32];
#pragma unroll
        for (int r = 0; r < 16; ++r) {
            int pair = (r & 3) + 8 * (r >> 2) + 4 * hi;
            rn[r] = rnormv[(i0 + (pair >> 3)) * 256 + (j0 + (pair & 7))];
        }
    }

    // ---- write outer tile into P[32 pairs][1024] bf16 (kc' = e*32+c), swizzled.
    // m = wr*64+mi*16+q16*4+r (i_loc = m>>5, c = m&31); n = wc*64+nj*16+l15.
#pragma unroll
    for (int mi = 0; mi < 4; ++mi)
#pragma unroll
        for (int nj = 0; nj < 4; ++nj) {
            int m = wr * 64 + mi * 16 + (q16 << 2);
            int n = wc * 64 + nj * 16 + l15;
            int pr = ((m >> 5) << 3) | (n >> 5);
            int c0 = m & 31, e = n & 31;
            int byte = pr * 2048 + (e * 32 + c0) * 2;
            byte ^= ((pr ^ e) & 7) << 4;
            u16x4 pk;
#pragma unroll
            for (int r = 0; r < 4; ++r)
                pk[r] = bf16bits(acc[mi][nj][r]);
            *(u16x4*)((char*)sh + byte) = pk;
        }
    __syncthreads();

    // ---- GEMM2 (waves 0-3): P[32 x 1024] @ WT^T -> [32 x 128], 32x32x16 MFMA
    if (wid < 4) {
        f32x16 a0 = {}, a1 = {};

        auto paddr = [&](int ks) {
            int kc = ks * 16 + hi * 8;
            int byte = p32 * 2048 + kc * 2;
            byte ^= ((p32 ^ (kc >> 5)) & 7) << 4;
            return (const bf16x8*)((const char*)sh + byte);
        };
        bf16x8 pa0 = *paddr(0), pa1 = *paddr(1);

#pragma unroll
        for (int ks = 0; ks < 64; ++ks) {
            bf16x8 cur = (ks & 1) ? pa1 : pa0;
            if (ks + 2 < 64) {
                if (ks & 1) pa1 = *paddr(ks + 2);
                else        pa0 = *paddr(ks + 2);
            }
            if (ks & 1)
                a1 = __builtin_amdgcn_mfma_f32_32x32x16_bf16(cur, wbr[ks & 7], a1, 0, 0, 0);
            else
                a0 = __builtin_amdgcn_mfma_f32_32x32x16_bf16(cur, wbr[ks & 7], a0, 0, 0, 0);
            if (ks + 8 < 64)
                wbr[ks & 7] = *(const bf16x8*)(wtrow + (ks + 8) * 16);
        }

        // epilogue: pair = (r&3)+8*(r>>2)+4*hi, z = z0+p32
        const int z = z0 + p32;
#pragma unroll
        for (int r = 0; r < 16; ++r) {
            int pair = (r & 3) + 8 * (r >> 2) + 4 * hi;
            int i = i0 + (pair >> 3), j = j0 + (pair & 7);
            float val = (a0[r] + a1[r] + bz) * rn[r];
            out[((size_t)(i * 256 + j)) * 128 + z] = val;
        }
    }
}

// ---------------------------------------------------------------------------
extern "C" void kernel_launch(void* const* d_in, const int* in_sizes, int n_in,
                              void* d_out, int out_size, void* d_ws, size_t ws_size,
                              hipStream_t stream) {
    const float* M    = (const float*)d_in[0];
    const float* mask = (const float*)d_in[1];
    const float* lnw  = (const float*)d_in[2];
    const float* lnb  = (const float*)d_in[3];
    const float* w1   = (const float*)d_in[4];
    const float* b1   = (const float*)d_in[5];
    const float* w2   = (const float*)d_in[6];
    const float* b2   = (const float*)d_in[7];
    const float* wout = (const float*)d_in[8];
    const float* bout = (const float*)d_in[9];
    float* out = (float*)d_out;

    char* ws = (char*)d_ws;
    u16*   AT    = (u16*)(ws);                 // [8192][256] bf16 = 4 MB
    u16*   BT    = (u16*)(ws + 4194304);       // 4 MB
    u16*   WT    = (u16*)(ws + 8388608);       // [128][1024] bf16 = 256 KB
    float* rnormv= (float*)(ws + 8650752);     // [256][256] f32 = 256 KB
    u16*   WcatT = (u16*)(ws + 8912896);       // [64][256] bf16 = 32 KB

    k_prep  <<<832, 256, 0, stream>>>(wout, mask, w1, w2, WT, WcatT, rnormv);
    k_lnproj<<<dim3(256, 4), 256, 0, stream>>>(M, mask, lnw, lnb, b1, b2, WcatT, AT, BT);
    k_fused <<<2048, 512, 0, stream>>>(AT, BT, WT, rnormv, bout, out);
}

// Round 11
// 155.013 us; speedup vs baseline: 1.3304x; 1.3304x over previous
//
#include <hip/hip_runtime.h>
#include <hip/hip_bf16.h>
#include <stdint.h>

typedef __bf16 bf16x8 __attribute__((ext_vector_type(8)));
typedef float  f32x4  __attribute__((ext_vector_type(4)));
typedef float  f32x16 __attribute__((ext_vector_type(16)));
typedef __attribute__((address_space(1))) uint32_t u32_g;
typedef __attribute__((address_space(3))) uint32_t u32_l;
typedef unsigned short u16;
typedef u16 u16x4 __attribute__((ext_vector_type(4)));

__device__ __forceinline__ void gload16(const void* g, void* l) {
    __builtin_amdgcn_global_load_lds((u32_g*)g, (u32_l*)l, 16, 0, 0);
}

__device__ __forceinline__ u16 bf16bits(float v) {
    __bf16 h = (__bf16)v;
    return __builtin_bit_cast(u16, h);
}

#define WAITV(n) asm volatile("s_waitcnt vmcnt(" #n ")" ::: "memory")
#define BAR() do { __builtin_amdgcn_s_barrier(); \
                   __builtin_amdgcn_sched_barrier(0); } while (0)

// ---------------------------------------------------------------------------
// k_prep:
//   b <  512 : WT[z][kc'] = bf16(w_out[c*32+e][z]),  kc' = e*32 + c
//   b <  576 : WcatT[n][k] = bf16(n<32 ? w1[k][n] : w2[k][n-32])
//   else     : rnorm[i][j] = 1 / (mask^T mask + 1e-3), one block per i
// ---------------------------------------------------------------------------
__global__ __launch_bounds__(256) void k_prep(const float* __restrict__ w_out,
                                              const float* __restrict__ mask,
                                              const float* __restrict__ w1,
                                              const float* __restrict__ w2,
                                              u16* __restrict__ WT,
                                              u16* __restrict__ WcatT,
                                              float* __restrict__ rnormv) {
    __shared__ float mcol[256];
    const int b = blockIdx.x, t = threadIdx.x;
    if (b < 512) {
        int idx = b * 256 + t;            // z*1024 + kc'
        int z = idx >> 10, kc = idx & 1023;
        int c = kc & 31, e = kc >> 5;
        WT[idx] = bf16bits(w_out[(c * 32 + e) * 128 + z]);
    } else if (b < 576) {
        int idx = (b - 512) * 256 + t;
        int n = idx >> 8, k = idx & 255;
        float v = (n < 32) ? w1[k * 32 + n] : w2[k * 32 + (n - 32)];
        WcatT[idx] = bf16bits(v);
    } else {
        int i = b - 576;
        mcol[t] = mask[(size_t)t * 256 + i];
        __syncthreads();
        float acc = 1e-3f;
#pragma unroll 8
        for (int s = 0; s < 256; ++s)
            acc += mcol[s] * mask[(size_t)s * 256 + t];
        rnormv[i * 256 + t] = 1.0f / acc;
    }
}

// ---------------------------------------------------------------------------
// k_lnproj: LayerNorm + dual projection via MFMA (unchanged).
// ---------------------------------------------------------------------------
__global__ __launch_bounds__(256, 2) void k_lnproj(
        const float* __restrict__ M, const float* __restrict__ mask,
        const float* __restrict__ lnw, const float* __restrict__ lnb,
        const float* __restrict__ b1, const float* __restrict__ b2,
        const u16* __restrict__ WcatT,
        u16* __restrict__ AT, u16* __restrict__ BT) {
    __shared__ __align__(16) u16 sh[32768];   // 64 KB
    const int tid = threadIdx.x, lane = tid & 63, w = tid >> 6;
    const int i = blockIdx.x, s0 = blockIdx.y * 64;

#pragma unroll
    for (int p = 0; p < 8; ++p) {
        int flat = p * 256 + tid;
        int r = flat >> 5, slot = flat & 31;
        int gs = slot ^ (r & 7);
        const char* src = (const char*)WcatT + (size_t)r * 512 + (size_t)gs * 16;
        char* dst = (char*)sh + 32768 + (size_t)(p * 256 + (tid & ~63)) * 16;
        gload16(src, dst);
    }

    float4 wv = *(const float4*)(lnw + lane * 4);
    float4 bv = *(const float4*)(lnb + lane * 4);
    float4 xv[16];
#pragma unroll
    for (int it = 0; it < 16; ++it) {
        int s = s0 + w * 16 + it;
        xv[it] = *(const float4*)(M + ((size_t)s * 256 + i) * 256 + lane * 4);
    }
#pragma unroll
    for (int it = 0; it < 16; ++it) {
        int row = w * 16 + it;
        float4 x = xv[it];
        float s1 = x.x + x.y + x.z + x.w;
        float s2 = x.x * x.x + x.y * x.y + x.z * x.z + x.w * x.w;
#pragma unroll
        for (int o = 1; o < 64; o <<= 1) {
            s1 += __shfl_xor(s1, o);
            s2 += __shfl_xor(s2, o);
        }
        float mu   = s1 * 0.00390625f;
        float var  = s2 * 0.00390625f - mu * mu;
        float rstd = rsqrtf(var + 1e-5f);
        u16x4 pk;
        pk[0] = bf16bits((x.x - mu) * rstd * wv.x + bv.x);
        pk[1] = bf16bits((x.y - mu) * rstd * wv.y + bv.y);
        pk[2] = bf16bits((x.z - mu) * rstd * wv.z + bv.z);
        pk[3] = bf16bits((x.w - mu) * rstd * wv.w + bv.w);
        int byte = (row * 512 + lane * 8) ^ ((row & 7) << 4);
        *(u16x4*)((char*)sh + byte) = pk;
    }
    __syncthreads();

    f32x4 acc[4] = {};
#pragma unroll
    for (int kk = 0; kk < 8; ++kk) {
        int kb = kk * 64 + ((lane >> 4) << 4);
        int arow = w * 16 + (lane & 15);
        bf16x8 af = *(const bf16x8*)((const char*)sh +
                     ((arow * 512 + kb) ^ ((arow & 7) << 4)));
#pragma unroll
        for (int f = 0; f < 4; ++f) {
            int nrow = f * 16 + (lane & 15);
            bf16x8 bfr = *(const bf16x8*)((const char*)sh + 32768 +
                          ((nrow * 512 + kb) ^ ((nrow & 7) << 4)));
            acc[f] = __builtin_amdgcn_mfma_f32_16x16x32_bf16(af, bfr, acc[f], 0, 0, 0);
        }
    }

    const int sb = s0 + w * 16 + ((lane >> 4) << 2);
    float mk[4];
#pragma unroll
    for (int r = 0; r < 4; ++r) mk[r] = mask[(size_t)(sb + r) * 256 + i];
#pragma unroll
    for (int f = 0; f < 4; ++f) {
        int col = f * 16 + (lane & 15);
        float bias = (col < 32) ? b1[col] : b2[col - 32];
        u16* dst = ((col < 32) ? AT : BT) + ((size_t)i * 32 + (col & 31)) * 256 + sb;
        u16x4 pk;
#pragma unroll
        for (int r = 0; r < 4; ++r)
            pk[r] = bf16bits((acc[f][r] + bias) * mk[r]);
        *(u16x4*)dst = pk;
    }
}

// ---------------------------------------------------------------------------
// k_fused v11: GEMM1 with A panel fully staged in LDS once (64KB, swizzled),
// B register-double-buffered direct from L2 (1 tile ahead, static indices).
// ZERO barriers in the K-loop. P[32][1024] overlays the A region afterwards.
// GEMM2 = R9 (4 waves, 32x32x16, hoisted WT/rnorm loads). LDS 64KB -> 2/CU.
// ---------------------------------------------------------------------------
__global__ __launch_bounds__(512, 4) void k_fused(
        const u16* __restrict__ AT, const u16* __restrict__ BT,
        const u16* __restrict__ WT, const float* __restrict__ rnormv,
        const float* __restrict__ b_out, float* __restrict__ out) {
    __shared__ __align__(16) u16 sh[32768];   // 64 KB: A[128][256] then P[32][1024]
    const int tid  = threadIdx.x;
    const int lane = tid & 63;
    const int wid  = tid >> 6;
    const int wr   = wid >> 2, wc = wid & 3;   // GEMM1: 2 x 4 wave grid
    const int l15  = lane & 15;
    const int q16  = lane >> 4;
    // Square-region XCD mapping (R9): XCD x owns a 16x16 (bx,by) region.
    const int lid = blockIdx.x;
    const int x   = lid & 7;
    const int kk_ = lid >> 3;                  // 0..255
    const int bx  = (x & 3) * 16 + (kk_ & 15);
    const int by  = (x >> 2) * 16 + (kk_ >> 4);
    const int m0 = bx * 128, n0 = by * 256;

    f32x4 acc[4][4] = {};

    // ---- stage whole A panel [128][256] bf16 = 64KB, slot-swizzled ----
    // linear dest; source slot gs = slot ^ (row&7) (32 slots of 16B per row)
#pragma unroll
    for (int p = 0; p < 8; ++p) {
        int flat = p * 512 + tid;               // 16B chunk id, 0..4095
        int r = flat >> 5, slot = flat & 31;
        int gs = slot ^ (r & 7);
        gload16((const char*)AT + (size_t)(m0 + r) * 512 + (size_t)gs * 16,
                (char*)sh + (size_t)(p * 512 + (tid & ~63)) * 16);
    }

    // B operand: register double-buffer, 1 k-tile (BK=32) ahead
    const u16* Bbase = BT + (size_t)(n0 + wc * 64 + l15) * 256 + q16 * 8;
    bf16x8 bfa[4], bfb[4];
#pragma unroll
    for (int nj = 0; nj < 4; ++nj)
        bfa[nj] = *(const bf16x8*)(Bbase + (size_t)nj * 4096);

    WAITV(0);      // A panel landed (bfa too)
    BAR();

    // ---- K-loop: 8 tiles of BK=32, no barriers, hand-unrolled x2 ----
    const char* shA = (const char*)sh;
    auto mfma16 = [&](const bf16x8 (&bf)[4], int t) {
        bf16x8 af[4];
#pragma unroll
        for (int mi = 0; mi < 4; ++mi) {
            int rA = wr * 64 + mi * 16 + l15;
            int slotIdx = (t * 4 + q16) ^ (rA & 7);
            af[mi] = *(const bf16x8*)(shA + rA * 512 + slotIdx * 16);
        }
        __builtin_amdgcn_s_setprio(1);
#pragma unroll
        for (int mi = 0; mi < 4; ++mi)
#pragma unroll
            for (int nj = 0; nj < 4; ++nj)
                acc[mi][nj] = __builtin_amdgcn_mfma_f32_16x16x32_bf16(
                    af[mi], bf[nj], acc[mi][nj], 0, 0, 0);
        __builtin_amdgcn_s_setprio(0);
    };

#pragma unroll
    for (int td = 0; td < 4; ++td) {
        const int t0 = td * 2;
        // prefetch tile t0+1 into bfb, then compute t0 with bfa
#pragma unroll
        for (int nj = 0; nj < 4; ++nj)
            bfb[nj] = *(const bf16x8*)(Bbase + (size_t)nj * 4096 + (t0 + 1) * 32);
        mfma16(bfa, t0);
        // prefetch tile t0+2 into bfa, then compute t0+1 with bfb
        if (td < 3) {
#pragma unroll
            for (int nj = 0; nj < 4; ++nj)
                bfa[nj] = *(const bf16x8*)(Bbase + (size_t)nj * 4096 + (t0 + 2) * 32);
        }
        mfma16(bfb, t0 + 1);
    }

    // ---- hoisted GEMM2 / epilogue loads (no dependency on P) ----
    const int z0  = (wid & 3) * 32;
    const int hi  = lane >> 5;         // 0/1
    const int p32 = lane & 31;
    const u16* wtrow = WT + (size_t)(z0 + p32) * 1024 + hi * 8;
    const int i0 = bx * 4, j0 = by * 8;
    bf16x8 wbr[8];
    float  rn[16];
    float  bz = 0.f;
    if (wid < 4) {
#pragma unroll
        for (int d = 0; d < 8; ++d)
            wbr[d] = *(const bf16x8*)(wtrow + d * 16);
        bz = b_out[z0 + p32];
#pragma unroll
        for (int r = 0; r < 16; ++r) {
            int pair = (r & 3) + 8 * (r >> 2) + 4 * hi;
            rn[r] = rnormv[(i0 + (pair >> 3)) * 256 + (j0 + (pair & 7))];
        }
    }

    BAR();   // all waves done reading A before P overwrites it

    // ---- write outer tile into P[32 pairs][1024] bf16 (kc' = e*32+c), swizzled.
#pragma unroll
    for (int mi = 0; mi < 4; ++mi)
#pragma unroll
        for (int nj = 0; nj < 4; ++nj) {
            int m = wr * 64 + mi * 16 + (q16 << 2);
            int n = wc * 64 + nj * 16 + l15;
            int pr = ((m >> 5) << 3) | (n >> 5);
            int c0 = m & 31, e = n & 31;
            int byte = pr * 2048 + (e * 32 + c0) * 2;
            byte ^= ((pr ^ e) & 7) << 4;
            u16x4 pk;
#pragma unroll
            for (int r = 0; r < 4; ++r)
                pk[r] = bf16bits(acc[mi][nj][r]);
            *(u16x4*)((char*)sh + byte) = pk;
        }
    __syncthreads();

    // ---- GEMM2 (waves 0-3): P[32 x 1024] @ WT^T -> [32 x 128], 32x32x16 MFMA
    if (wid < 4) {
        f32x16 a0 = {}, a1 = {};

        auto paddr = [&](int ks) {
            int kc = ks * 16 + hi * 8;
            int byte = p32 * 2048 + kc * 2;
            byte ^= ((p32 ^ (kc >> 5)) & 7) << 4;
            return (const bf16x8*)((const char*)sh + byte);
        };
        bf16x8 pa0 = *paddr(0), pa1 = *paddr(1);

#pragma unroll
        for (int ks = 0; ks < 64; ++ks) {
            bf16x8 cur = (ks & 1) ? pa1 : pa0;
            if (ks + 2 < 64) {
                if (ks & 1) pa1 = *paddr(ks + 2);
                else        pa0 = *paddr(ks + 2);
            }
            if (ks & 1)
                a1 = __builtin_amdgcn_mfma_f32_32x32x16_bf16(cur, wbr[ks & 7], a1, 0, 0, 0);
            else
                a0 = __builtin_amdgcn_mfma_f32_32x32x16_bf16(cur, wbr[ks & 7], a0, 0, 0, 0);
            if (ks + 8 < 64)
                wbr[ks & 7] = *(const bf16x8*)(wtrow + (ks + 8) * 16);
        }

        // epilogue: pair = (r&3)+8*(r>>2)+4*hi, z = z0+p32
        const int z = z0 + p32;
#pragma unroll
        for (int r = 0; r < 16; ++r) {
            int pair = (r & 3) + 8 * (r >> 2) + 4 * hi;
            int i = i0 + (pair >> 3), j = j0 + (pair & 7);
            float val = (a0[r] + a1[r] + bz) * rn[r];
            out[((size_t)(i * 256 + j)) * 128 + z] = val;
        }
    }
}

// ---------------------------------------------------------------------------
extern "C" void kernel_launch(void* const* d_in, const int* in_sizes, int n_in,
                              void* d_out, int out_size, void* d_ws, size_t ws_size,
                              hipStream_t stream) {
    const float* M    = (const float*)d_in[0];
    const float* mask = (const float*)d_in[1];
    const float* lnw  = (const float*)d_in[2];
    const float* lnb  = (const float*)d_in[3];
    const float* w1   = (const float*)d_in[4];
    const float* b1   = (const float*)d_in[5];
    const float* w2   = (const float*)d_in[6];
    const float* b2   = (const float*)d_in[7];
    const float* wout = (const float*)d_in[8];
    const float* bout = (const float*)d_in[9];
    float* out = (float*)d_out;

    char* ws = (char*)d_ws;
    u16*   AT    = (u16*)(ws);                 // [8192][256] bf16 = 4 MB
    u16*   BT    = (u16*)(ws + 4194304);       // 4 MB
    u16*   WT    = (u16*)(ws + 8388608);       // [128][1024] bf16 = 256 KB
    float* rnormv= (float*)(ws + 8650752);     // [256][256] f32 = 256 KB
    u16*   WcatT = (u16*)(ws + 8912896);       // [64][256] bf16 = 32 KB

    k_prep  <<<832, 256, 0, stream>>>(wout, mask, w1, w2, WT, WcatT, rnormv);
    k_lnproj<<<dim3(256, 4), 256, 0, stream>>>(M, mask, lnw, lnb, b1, b2, WcatT, AT, BT);
    k_fused <<<2048, 512, 0, stream>>>(AT, BT, WT, rnormv, bout, out);
}

// Round 12
// 118.221 us; speedup vs baseline: 1.7445x; 1.3112x over previous
//
#include <hip/hip_runtime.h>
#include <hip/hip_bf16.h>
#include <stdint.h>

typedef __bf16 bf16x8 __attribute__((ext_vector_type(8)));
typedef float  f32x4  __attribute__((ext_vector_type(4)));
typedef float  f32x16 __attribute__((ext_vector_type(16)));
typedef __attribute__((address_space(1))) uint32_t u32_g;
typedef __attribute__((address_space(3))) uint32_t u32_l;
typedef unsigned short u16;
typedef u16 u16x4 __attribute__((ext_vector_type(4)));

__device__ __forceinline__ void gload16(const void* g, void* l) {
    __builtin_amdgcn_global_load_lds((u32_g*)g, (u32_l*)l, 16, 0, 0);
}

__device__ __forceinline__ u16 bf16bits(float v) {
    __bf16 h = (__bf16)v;
    return __builtin_bit_cast(u16, h);
}

#define WAITV(n) asm volatile("s_waitcnt vmcnt(" #n ")" ::: "memory")
#define BAR() do { __builtin_amdgcn_s_barrier(); \
                   __builtin_amdgcn_sched_barrier(0); } while (0)

// ---------------------------------------------------------------------------
// k_prep:
//   b <  512 : WT[z][kc'] = bf16(w_out[c*32+e][z]),  kc' = e*32 + c
//   b <  576 : WcatT[n][k] = bf16(n<32 ? w1[k][n] : w2[k][n-32])
//   else     : rnorm[i][j] = 1 / (mask^T mask + 1e-3), one block per i
// ---------------------------------------------------------------------------
__global__ __launch_bounds__(256) void k_prep(const float* __restrict__ w_out,
                                              const float* __restrict__ mask,
                                              const float* __restrict__ w1,
                                              const float* __restrict__ w2,
                                              u16* __restrict__ WT,
                                              u16* __restrict__ WcatT,
                                              float* __restrict__ rnormv) {
    __shared__ float mcol[256];
    const int b = blockIdx.x, t = threadIdx.x;
    if (b < 512) {
        int idx = b * 256 + t;            // z*1024 + kc'
        int z = idx >> 10, kc = idx & 1023;
        int c = kc & 31, e = kc >> 5;
        WT[idx] = bf16bits(w_out[(c * 32 + e) * 128 + z]);
    } else if (b < 576) {
        int idx = (b - 512) * 256 + t;
        int n = idx >> 8, k = idx & 255;
        float v = (n < 32) ? w1[k * 32 + n] : w2[k * 32 + (n - 32)];
        WcatT[idx] = bf16bits(v);
    } else {
        int i = b - 576;
        mcol[t] = mask[(size_t)t * 256 + i];
        __syncthreads();
        float acc = 1e-3f;
#pragma unroll 8
        for (int s = 0; s < 256; ++s)
            acc += mcol[s] * mask[(size_t)s * 256 + t];
        rnormv[i * 256 + t] = 1.0f / acc;
    }
}

// ---------------------------------------------------------------------------
// k_lnproj: LayerNorm + dual projection via MFMA (unchanged).
// ---------------------------------------------------------------------------
__global__ __launch_bounds__(256, 2) void k_lnproj(
        const float* __restrict__ M, const float* __restrict__ mask,
        const float* __restrict__ lnw, const float* __restrict__ lnb,
        const float* __restrict__ b1, const float* __restrict__ b2,
        const u16* __restrict__ WcatT,
        u16* __restrict__ AT, u16* __restrict__ BT) {
    __shared__ __align__(16) u16 sh[32768];   // 64 KB
    const int tid = threadIdx.x, lane = tid & 63, w = tid >> 6;
    const int i = blockIdx.x, s0 = blockIdx.y * 64;

#pragma unroll
    for (int p = 0; p < 8; ++p) {
        int flat = p * 256 + tid;
        int r = flat >> 5, slot = flat & 31;
        int gs = slot ^ (r & 7);
        const char* src = (const char*)WcatT + (size_t)r * 512 + (size_t)gs * 16;
        char* dst = (char*)sh + 32768 + (size_t)(p * 256 + (tid & ~63)) * 16;
        gload16(src, dst);
    }

    float4 wv = *(const float4*)(lnw + lane * 4);
    float4 bv = *(const float4*)(lnb + lane * 4);
    float4 xv[16];
#pragma unroll
    for (int it = 0; it < 16; ++it) {
        int s = s0 + w * 16 + it;
        xv[it] = *(const float4*)(M + ((size_t)s * 256 + i) * 256 + lane * 4);
    }
#pragma unroll
    for (int it = 0; it < 16; ++it) {
        int row = w * 16 + it;
        float4 x = xv[it];
        float s1 = x.x + x.y + x.z + x.w;
        float s2 = x.x * x.x + x.y * x.y + x.z * x.z + x.w * x.w;
#pragma unroll
        for (int o = 1; o < 64; o <<= 1) {
            s1 += __shfl_xor(s1, o);
            s2 += __shfl_xor(s2, o);
        }
        float mu   = s1 * 0.00390625f;
        float var  = s2 * 0.00390625f - mu * mu;
        float rstd = rsqrtf(var + 1e-5f);
        u16x4 pk;
        pk[0] = bf16bits((x.x - mu) * rstd * wv.x + bv.x);
        pk[1] = bf16bits((x.y - mu) * rstd * wv.y + bv.y);
        pk[2] = bf16bits((x.z - mu) * rstd * wv.z + bv.z);
        pk[3] = bf16bits((x.w - mu) * rstd * wv.w + bv.w);
        int byte = (row * 512 + lane * 8) ^ ((row & 7) << 4);
        *(u16x4*)((char*)sh + byte) = pk;
    }
    __syncthreads();

    f32x4 acc[4] = {};
#pragma unroll
    for (int kk = 0; kk < 8; ++kk) {
        int kb = kk * 64 + ((lane >> 4) << 4);
        int arow = w * 16 + (lane & 15);
        bf16x8 af = *(const bf16x8*)((const char*)sh +
                     ((arow * 512 + kb) ^ ((arow & 7) << 4)));
#pragma unroll
        for (int f = 0; f < 4; ++f) {
            int nrow = f * 16 + (lane & 15);
            bf16x8 bfr = *(const bf16x8*)((const char*)sh + 32768 +
                          ((nrow * 512 + kb) ^ ((nrow & 7) << 4)));
            acc[f] = __builtin_amdgcn_mfma_f32_16x16x32_bf16(af, bfr, acc[f], 0, 0, 0);
        }
    }

    const int sb = s0 + w * 16 + ((lane >> 4) << 2);
    float mk[4];
#pragma unroll
    for (int r = 0; r < 4; ++r) mk[r] = mask[(size_t)(sb + r) * 256 + i];
#pragma unroll
    for (int f = 0; f < 4; ++f) {
        int col = f * 16 + (lane & 15);
        float bias = (col < 32) ? b1[col] : b2[col - 32];
        u16* dst = ((col < 32) ? AT : BT) + ((size_t)i * 32 + (col & 31)) * 256 + sb;
        u16x4 pk;
#pragma unroll
        for (int r = 0; r < 4; ++r)
            pk[r] = bf16bits((acc[f][r] + bias) * mk[r]);
        *(u16x4*)dst = pk;
    }
}

// ---------------------------------------------------------------------------
// k_fused v12: GEMM1 = R8 (A+B staged LDS, 3 bufs x 24KB, depth-2, vmcnt(3),
// slot swizzle s^=(r>>1)&3; square-XCD map). GEMM2 k-split over ALL 8 waves:
// wave (half, slice): z in [slice*32,+32), kc in [half*512,+512), 32 iters of
// mfma 32x32x16; waves 4-7 dump f32x16 partials to LDS, waves 0-3 add+store.
// LDS 72 KB (P[32][1024] + 16KB red scratch overlay) -> 2 blocks/CU.
// ---------------------------------------------------------------------------
__global__ __launch_bounds__(512, 4) void k_fused(
        const u16* __restrict__ AT, const u16* __restrict__ BT,
        const u16* __restrict__ WT, const float* __restrict__ rnormv,
        const float* __restrict__ b_out, float* __restrict__ out) {
    __shared__ __align__(16) u16 sh[36864];   // 72 KB
    const int tid  = threadIdx.x;
    const int lane = tid & 63;
    const int wid  = tid >> 6;
    const int wr   = wid >> 2, wc = wid & 3;   // GEMM1: 2 x 4 wave grid
    const int l15  = lane & 15;
    const int q16  = lane >> 4;
    // Square-region XCD mapping: XCD x owns a 16x16 (bx,by) region.
    const int lid = blockIdx.x;
    const int x   = lid & 7;
    const int kk_ = lid >> 3;                  // 0..255
    const int bx  = (x & 3) * 16 + (kk_ & 15);
    const int by  = (x >> 2) * 16 + (kk_ >> 4);
    const int m0 = bx * 128, n0 = by * 256;

    f32x4 acc[4][4] = {};

    auto stage = [&](int kt, int buf) {
        char* base = (char*)sh + buf * 24576;
        const int k0 = kt * 32;
        {
            int r = tid >> 2, slot = tid & 3;
            int gs = slot ^ ((r >> 1) & 3);
            gload16((const char*)AT + (((size_t)(m0 + r)) * 256 + k0) * 2 + gs * 16,
                    base + (size_t)(tid & ~63) * 16);
        }
#pragma unroll
        for (int q = 0; q < 2; ++q) {
            int flat = q * 512 + tid;
            int r = flat >> 2, slot = flat & 3;
            int gs = slot ^ ((r >> 1) & 3);
            gload16((const char*)BT + (((size_t)(n0 + r)) * 256 + k0) * 2 + gs * 16,
                    base + 8192 + (size_t)(q * 512 + (tid & ~63)) * 16);
        }
    };

    auto compute = [&](int buf) {
        const char* Ab = (const char*)sh + buf * 24576;
        const char* Bb = Ab + 8192;
        bf16x8 af[4], bfr[4];
#pragma unroll
        for (int mi = 0; mi < 4; ++mi) {
            int rA = wr * 64 + mi * 16 + l15;
            af[mi] = *(const bf16x8*)(Ab + rA * 64 + (q16 ^ ((rA >> 1) & 3)) * 16);
        }
#pragma unroll
        for (int nj = 0; nj < 4; ++nj) {
            int rB = wc * 64 + nj * 16 + l15;
            bfr[nj] = *(const bf16x8*)(Bb + rB * 64 + (q16 ^ ((rB >> 1) & 3)) * 16);
        }
        __builtin_amdgcn_s_setprio(1);
#pragma unroll
        for (int mi = 0; mi < 4; ++mi)
#pragma unroll
            for (int nj = 0; nj < 4; ++nj)
                acc[mi][nj] = __builtin_amdgcn_mfma_f32_16x16x32_bf16(
                    af[mi], bfr[nj], acc[mi][nj], 0, 0, 0);
        __builtin_amdgcn_s_setprio(0);
    };

    // prologue: tiles 0,1 in flight; wait tile0 (tile1's 3 loads outstanding)
    stage(0, 0);
    stage(1, 1);
    WAITV(3);
    BAR();
#pragma unroll
    for (int t = 0; t < 8; ++t) {
        if (t + 2 < 8) stage(t + 2, (t + 2) % 3);
        compute(t % 3);
        if (t < 6) { WAITV(3); }
        else if (t == 6) { WAITV(0); }
        BAR();
    }

    // ---- write outer tile into P[32 pairs][1024] bf16 (kc' = e*32+c), swizzled.
#pragma unroll
    for (int mi = 0; mi < 4; ++mi)
#pragma unroll
        for (int nj = 0; nj < 4; ++nj) {
            int m = wr * 64 + mi * 16 + (q16 << 2);
            int n = wc * 64 + nj * 16 + l15;
            int pr = ((m >> 5) << 3) | (n >> 5);
            int c0 = m & 31, e = n & 31;
            int byte = pr * 2048 + (e * 32 + c0) * 2;
            byte ^= ((pr ^ e) & 7) << 4;
            u16x4 pk;
#pragma unroll
            for (int r = 0; r < 4; ++r)
                pk[r] = bf16bits(acc[mi][nj][r]);
            *(u16x4*)((char*)sh + byte) = pk;
        }
    __syncthreads();

    // ---- GEMM2 (ALL 8 waves): wave (half,slice): z [slice*32,+32),
    //      kc [half*512,+512), 32 iters of 32x32x16. Partials reduced via LDS.
    const int slice = wid & 3;
    const int half  = wid >> 2;
    const int z0  = slice * 32;
    const int hi  = lane >> 5;         // 0/1
    const int p32 = lane & 31;
    const u16* wtrow = WT + (size_t)(z0 + p32) * 1024 + half * 512 + hi * 8;

    f32x16 a0 = {}, a1 = {};
    bf16x8 wbr[8];
#pragma unroll
    for (int d = 0; d < 8; ++d)
        wbr[d] = *(const bf16x8*)(wtrow + d * 16);

    auto paddr = [&](int ks) {         // ks in [0,32)
        int kc = half * 512 + ks * 16 + hi * 8;
        int byte = p32 * 2048 + kc * 2;
        byte ^= ((p32 ^ (kc >> 5)) & 7) << 4;
        return (const bf16x8*)((const char*)sh + byte);
    };
    bf16x8 pa0 = *paddr(0), pa1 = *paddr(1);

#pragma unroll
    for (int ks = 0; ks < 32; ++ks) {
        bf16x8 cur = (ks & 1) ? pa1 : pa0;
        if (ks + 2 < 32) {
            if (ks & 1) pa1 = *paddr(ks + 2);
            else        pa0 = *paddr(ks + 2);
        }
        if (ks & 1)
            a1 = __builtin_amdgcn_mfma_f32_32x32x16_bf16(cur, wbr[ks & 7], a1, 0, 0, 0);
        else
            a0 = __builtin_amdgcn_mfma_f32_32x32x16_bf16(cur, wbr[ks & 7], a0, 0, 0, 0);
        if (ks + 8 < 32)
            wbr[ks & 7] = *(const bf16x8*)(wtrow + (ks + 8) * 16);
    }
#pragma unroll
    for (int r = 0; r < 16; ++r) a0[r] += a1[r];

    __syncthreads();                   // all waves done reading P
    float* red = (float*)sh;           // 16 KB scratch overlaying dead P
    if (half == 1) {
#pragma unroll
        for (int r = 0; r < 16; ++r)
            red[slice * 1024 + r * 64 + lane] = a0[r];
    }
    __syncthreads();

    if (half == 0) {
        const int i0 = bx * 4, j0 = by * 8;
        const int z  = z0 + p32;
        const float bz = b_out[z];
#pragma unroll
        for (int r = 0; r < 16; ++r) {
            float v = a0[r] + red[slice * 1024 + r * 64 + lane];
            int pair = (r & 3) + 8 * (r >> 2) + 4 * hi;
            int i = i0 + (pair >> 3), j = j0 + (pair & 7);
            out[((size_t)(i * 256 + j)) * 128 + z] =
                (v + bz) * rnormv[i * 256 + j];
        }
    }
}

// ---------------------------------------------------------------------------
extern "C" void kernel_launch(void* const* d_in, const int* in_sizes, int n_in,
                              void* d_out, int out_size, void* d_ws, size_t ws_size,
                              hipStream_t stream) {
    const float* M    = (const float*)d_in[0];
    const float* mask = (const float*)d_in[1];
    const float* lnw  = (const float*)d_in[2];
    const float* lnb  = (const float*)d_in[3];
    const float* w1   = (const float*)d_in[4];
    const float* b1   = (const float*)d_in[5];
    const float* w2   = (const float*)d_in[6];
    const float* b2   = (const float*)d_in[7];
    const float* wout = (const float*)d_in[8];
    const float* bout = (const float*)d_in[9];
    float* out = (float*)d_out;

    char* ws = (char*)d_ws;
    u16*   AT    = (u16*)(ws);                 // [8192][256] bf16 = 4 MB
    u16*   BT    = (u16*)(ws + 4194304);       // 4 MB
    u16*   WT    = (u16*)(ws + 8388608);       // [128][1024] bf16 = 256 KB
    float* rnormv= (float*)(ws + 8650752);     // [256][256] f32 = 256 KB
    u16*   WcatT = (u16*)(ws + 8912896);       // [64][256] bf16 = 32 KB

    k_prep  <<<832, 256, 0, stream>>>(wout, mask, w1, w2, WT, WcatT, rnormv);
    k_lnproj<<<dim3(256, 4), 256, 0, stream>>>(M, mask, lnw, lnb, b1, b2, WcatT, AT, BT);
    k_fused <<<2048, 512, 0, stream>>>(AT, BT, WT, rnormv, bout, out);
}